// Round 13
// baseline (124.368 us; speedup 1.0000x reference)
//
#include <hip/hip_runtime.h>

#define N_NODES 100000
#define N_EDGES 600000
#define D 128
#define K2 256          // stacked K = [agg | x]

#define NBUCKET 196        // ceil(N_NODES / 512); bucket = dst >> 9
#define SB_EPT 8
#define SB_EDGES (256 * SB_EPT)                          // 2048 edges/block
#define SB_BLOCKS ((N_EDGES + SB_EDGES - 1) / SB_EDGES)  // 293
#define CAPB 4608          // padded per-bucket capacity (mean 3072, sigma~55)

#define CONV_BLOCKS 6250   // N_NODES*16 / 256 exactly
#define WPREP_BLOCKS 16    // 4096 slots / 256

typedef __attribute__((ext_vector_type(8))) short short8;
typedef __attribute__((ext_vector_type(4))) float f32x4;

__device__ __forceinline__ unsigned short f2bf(float f) {
    union { float f; unsigned u; } v; v.f = f;
    unsigned u = v.u;
    u += 0x7FFFu + ((u >> 16) & 1u);     // round-to-nearest-even
    return (unsigned short)(u >> 16);
}

__device__ __forceinline__ float bf_lo(unsigned u) {
    union { unsigned u; float f; } v; v.u = u << 16; return v.f;
}
__device__ __forceinline__ float bf_hi(unsigned u) {
    union { unsigned u; float f; } v; v.u = u & 0xFFFF0000u; return v.f;
}

// ---------------------------------------------------------------------------
// mega: fused {convert_x | wprep | local_sort}.  All three block families
// are mutually independent (local_sort needs NO global state: each block
// writes its own edgeTmp region + per-block bucket offset table).
// ---------------------------------------------------------------------------
__global__ __launch_bounds__(256) void mega_kernel(
        const float* __restrict__ x,
        unsigned short* __restrict__ Amat,
        const float* __restrict__ Wrel,
        const float* __restrict__ Wroot,
        unsigned short* __restrict__ Wfrag,
        const int* __restrict__ ei,
        unsigned* __restrict__ edgeTmp,
        int* __restrict__ blockBucketOff) {
    __shared__ int cnt[NBUCKET];
    __shared__ int pos[NBUCKET];
    __shared__ int sh[256];
    int b = blockIdx.x;
    int tid = threadIdx.x;
    if (b < CONV_BLOCKS) {
        // convert_x: x fp32 -> Amat[:,128:256) bf16
        int t = b * 256 + tid;                  // < 1.6M exactly
        int n = t >> 4, c8 = (t & 15) * 8;
        const float4* p = (const float4*)&x[(size_t)n * D + c8];
        float4 v0 = p[0], v1 = p[1];
        uint4 o;
        o.x = (unsigned)f2bf(v0.x) | ((unsigned)f2bf(v0.y) << 16);
        o.y = (unsigned)f2bf(v0.z) | ((unsigned)f2bf(v0.w) << 16);
        o.z = (unsigned)f2bf(v1.x) | ((unsigned)f2bf(v1.y) << 16);
        o.w = (unsigned)f2bf(v1.z) | ((unsigned)f2bf(v1.w) << 16);
        *(uint4*)&Amat[(size_t)n * K2 + 128 + c8] = o;
    } else if (b < CONV_BLOCKS + WPREP_BLOCKS) {
        // wprep: pack [Wrel;Wroot] into MFMA B-fragment order, bf16.
        int slot = (b - CONV_BLOCKS) * 256 + tid;   // < 4096 exactly
        int lane = slot & 63;
        int ks = (slot >> 6) & 7;
        int ct = slot >> 9;
        int m = ct * 16 + (lane & 15);
        int k = ks * 32 + (lane >> 4) * 8;
        const float* src = (k < 128) ? &Wrel[(size_t)m * 128 + k]
                                     : &Wroot[(size_t)m * 128 + (k - 128)];
        uint4 o;
        o.x = (unsigned)f2bf(src[0]) | ((unsigned)f2bf(src[1]) << 16);
        o.y = (unsigned)f2bf(src[2]) | ((unsigned)f2bf(src[3]) << 16);
        o.z = (unsigned)f2bf(src[4]) | ((unsigned)f2bf(src[5]) << 16);
        o.w = (unsigned)f2bf(src[6]) | ((unsigned)f2bf(src[7]) << 16);
        *(uint4*)&Wfrag[(size_t)slot * 8] = o;
    } else {
        // local_sort: bucket-group this block's 2048 edges into its OWN
        // edgeTmp region; write per-block bucket offsets (197 ints).
        int sb = b - CONV_BLOCKS - WPREP_BLOCKS;
        for (int i = tid; i < NBUCKET; i += 256) cnt[i] = 0;
        __syncthreads();
        int e0 = sb * SB_EDGES + tid;
        unsigned pack[SB_EPT];
        int bk[SB_EPT], rk[SB_EPT];
#pragma unroll
        for (int j = 0; j < SB_EPT; ++j) {
            int e = e0 + j * 256;
            if (e < N_EDGES) {
                int s = ei[e];
                int d = ei[N_EDGES + e];
                pack[j] = (unsigned)s | ((unsigned)(d & 511) << 17);
                bk[j] = d >> 9;
                rk[j] = atomicAdd(&cnt[bk[j]], 1);
            } else bk[j] = -1;
        }
        __syncthreads();
        int v = (tid < NBUCKET) ? cnt[tid] : 0;
        sh[tid] = v;
        __syncthreads();
        for (int off = 1; off < 256; off <<= 1) {
            int u = (tid >= off) ? sh[tid - off] : 0;
            __syncthreads();
            sh[tid] += u;
            __syncthreads();
        }
        int excl = sh[tid] - v;             // tid==196 -> total valid count
        if (tid < NBUCKET) pos[tid] = excl;
        if (tid <= NBUCKET) blockBucketOff[sb * (NBUCKET + 1) + tid] = excl;
        __syncthreads();
#pragma unroll
        for (int j = 0; j < SB_EPT; ++j)
            if (bk[j] >= 0)
                edgeTmp[sb * SB_EDGES + pos[bk[j]] + rk[j]] = pack[j];
    }
}

// ---------------------------------------------------------------------------
// finalize: one block per bucket k.  Gathers the 293 per-block runs of
// bucket k into LDS staging (position-parallel binary search), counts/scans
// the 512 local dsts, writes per-node (beg,end) into offs2 and srcs into
// PADDED srcSortedPad[k*CAPB..].  No global scan anywhere.
// ---------------------------------------------------------------------------
__global__ __launch_bounds__(256) void finalize_kernel(
        const unsigned* __restrict__ edgeTmp,
        const int* __restrict__ blockBucketOff,
        int* __restrict__ offs2, int* __restrict__ srcSortedPad) {
    __shared__ unsigned eLDS[CAPB];      // 18 KB staging
    __shared__ int bs[512], bn[512], bp[513];
    __shared__ int cnt[512], cur[512];
    __shared__ int sh[256];
    int k = blockIdx.x, tid = threadIdx.x;

    for (int b = tid; b < 512; b += 256) { bn[b] = 0; bs[b] = 0; }
    cnt[tid] = 0; cnt[tid + 256] = 0;
    __syncthreads();
    for (int b = tid; b < SB_BLOCKS; b += 256) {
        int s = blockBucketOff[b * (NBUCKET + 1) + k];
        int e = blockBucketOff[b * (NBUCKET + 1) + k + 1];
        bs[b] = s;
        bn[b] = e - s;
    }
    __syncthreads();
    int c0 = bn[2 * tid], c1 = bn[2 * tid + 1];
    int ps = c0 + c1;
    sh[tid] = ps;
    __syncthreads();
    for (int off = 1; off < 256; off <<= 1) {
        int u = (tid >= off) ? sh[tid - off] : 0;
        __syncthreads();
        sh[tid] += u;
        __syncthreads();
    }
    int pexcl = sh[tid] - ps;
    bp[2 * tid] = pexcl;
    bp[2 * tid + 1] = pexcl + c0;
    __syncthreads();
    int total = bp[511] + bn[511];
    if (total > CAPB) total = CAPB;      // statistically impossible; safety
    if (tid == 0) bp[512] = total;
    __syncthreads();
    for (int p = tid; p < total; p += 256) {
        int lo = 0, hi = 511;            // largest r with bp[r] <= p
        while (lo < hi) {
            int mid = (lo + hi + 1) >> 1;
            if (bp[mid] <= p) lo = mid; else hi = mid - 1;
        }
        eLDS[p] = edgeTmp[lo * SB_EDGES + bs[lo] + (p - bp[lo])];
    }
    __syncthreads();
    for (int i = tid; i < total; i += 256)
        atomicAdd(&cnt[eLDS[i] >> 17], 1);
    __syncthreads();
    c0 = cnt[2 * tid]; c1 = cnt[2 * tid + 1];
    ps = c0 + c1;
    sh[tid] = ps;
    __syncthreads();
    for (int off = 1; off < 256; off <<= 1) {
        int u = (tid >= off) ? sh[tid - off] : 0;
        __syncthreads();
        sh[tid] += u;
        __syncthreads();
    }
    int base = k * CAPB;
    pexcl = sh[tid] - ps + base;
    cur[2 * tid] = pexcl;
    cur[2 * tid + 1] = pexcl + c0;
    int d = (k << 9) + 2 * tid;
    if (d < N_NODES) {
        offs2[2 * d] = pexcl;
        offs2[2 * d + 1] = pexcl + c0;
    }
    if (d + 1 < N_NODES) {
        offs2[2 * d + 2] = pexcl + c0;
        offs2[2 * d + 3] = pexcl + c0 + c1;
    }
    __syncthreads();
    for (int i = tid; i < total; i += 256) {
        unsigned p = eLDS[i];
        int posn = atomicAdd(&cur[p >> 17], 1);
        srcSortedPad[posn] = (int)(p & 0x1FFFFu);
    }
}

// ---------------------------------------------------------------------------
// gather_gemm: fused seg_sum + GEMM.  782 blocks x 512 threads x 128 rows.
// LDS 96 KB = W (64 KB, reused by epilogue) + A-lds (32 KB, XOR-swizzled).
//   phase 1: stage W.
//   phase 2: gather - quarter-wave (16 lanes x 16B = full 256B bf16 row per
//            load) per node, 4 nodes/wave/iter, 4-deep edge gathers; agg
//            accumulated fp32, packed bf16 into A-lds (NO global agg
//            round-trip: deletes 51.2 MB of traffic vs split kernels).
//   phase 3: MFMA - ks 0..3 A-frags from A-lds, ks 4..7 (x-half) preloaded
//            from global Amat; B from W-lds.
//   phase 4: epilogue via swizzled-LDS transpose (reuses W region) +
//            fully-coalesced float4 stores.
// A-lds swizzle byte = r*256 + (c*2 ^ ((r&7)<<4)): conflict-free for both
// the gather writes and the MFMA fragment reads (2-way max = free).
// ---------------------------------------------------------------------------
__global__ __launch_bounds__(512, 2) void gather_gemm(
        const unsigned short* __restrict__ Amat,
        const unsigned short* __restrict__ Wfrag,
        const int* __restrict__ offs2,
        const int* __restrict__ srcSortedPad,
        const float* __restrict__ brel,
        float* __restrict__ out) {
    __shared__ __align__(16) char smem[98304];  // [0,64K) W/epilogue, [64K,96K) A-lds
    short8* Wlds = (short8*)smem;
    char*   Alds = smem + 65536;
    float*  So   = (float*)smem;

    int tid = threadIdx.x;
    for (int i = tid; i < 4096; i += 512)
        Wlds[i] = *(const short8*)&Wfrag[(size_t)i * 8];

    int lane = tid & 63;
    int w = tid >> 6;                    // 0..7
    long rowB = (long)blockIdx.x * 128;

    // ---- gather phase: wave w owns block-local rows [w*16, w*16+16) ----
    {
        int q = lane >> 4;               // quarter 0..3
        int c8 = (lane & 15) * 8;        // 8 bf16 cols = 16 B per lane
        for (int it = 0; it < 4; ++it) {
            int rl = w * 16 + it * 4 + q;
            long node = rowB + rl;
            if (node < N_NODES) {
                int2 be = *(const int2*)&offs2[2 * node];
                int beg = be.x, end = be.y;
                float a0 = 0, a1 = 0, a2 = 0, a3 = 0, a4 = 0, a5 = 0, a6 = 0, a7 = 0;
                int p = beg;
                for (; p + 3 < end; p += 4) {    // 4 independent gathers
                    int s0 = srcSortedPad[p],     s1 = srcSortedPad[p + 1];
                    int s2 = srcSortedPad[p + 2], s3 = srcSortedPad[p + 3];
                    uint4 u0 = *(const uint4*)&Amat[(size_t)s0 * K2 + 128 + c8];
                    uint4 u1 = *(const uint4*)&Amat[(size_t)s1 * K2 + 128 + c8];
                    uint4 u2 = *(const uint4*)&Amat[(size_t)s2 * K2 + 128 + c8];
                    uint4 u3 = *(const uint4*)&Amat[(size_t)s3 * K2 + 128 + c8];
                    a0 += (bf_lo(u0.x) + bf_lo(u1.x)) + (bf_lo(u2.x) + bf_lo(u3.x));
                    a1 += (bf_hi(u0.x) + bf_hi(u1.x)) + (bf_hi(u2.x) + bf_hi(u3.x));
                    a2 += (bf_lo(u0.y) + bf_lo(u1.y)) + (bf_lo(u2.y) + bf_lo(u3.y));
                    a3 += (bf_hi(u0.y) + bf_hi(u1.y)) + (bf_hi(u2.y) + bf_hi(u3.y));
                    a4 += (bf_lo(u0.z) + bf_lo(u1.z)) + (bf_lo(u2.z) + bf_lo(u3.z));
                    a5 += (bf_hi(u0.z) + bf_hi(u1.z)) + (bf_hi(u2.z) + bf_hi(u3.z));
                    a6 += (bf_lo(u0.w) + bf_lo(u1.w)) + (bf_lo(u2.w) + bf_lo(u3.w));
                    a7 += (bf_hi(u0.w) + bf_hi(u1.w)) + (bf_hi(u2.w) + bf_hi(u3.w));
                }
                for (; p < end; ++p) {
                    int s0 = srcSortedPad[p];
                    uint4 u0 = *(const uint4*)&Amat[(size_t)s0 * K2 + 128 + c8];
                    a0 += bf_lo(u0.x); a1 += bf_hi(u0.x);
                    a2 += bf_lo(u0.y); a3 += bf_hi(u0.y);
                    a4 += bf_lo(u0.z); a5 += bf_hi(u0.z);
                    a6 += bf_lo(u0.w); a7 += bf_hi(u0.w);
                }
                uint4 o;
                o.x = (unsigned)f2bf(a0) | ((unsigned)f2bf(a1) << 16);
                o.y = (unsigned)f2bf(a2) | ((unsigned)f2bf(a3) << 16);
                o.z = (unsigned)f2bf(a4) | ((unsigned)f2bf(a5) << 16);
                o.w = (unsigned)f2bf(a6) | ((unsigned)f2bf(a7) << 16);
                *(uint4*)&Alds[rl * 256 + ((c8 * 2) ^ ((rl & 7) << 4))] = o;
            }
        }
    }
    __syncthreads();   // W staged + A-lds filled

    // ---- MFMA phase ----
    int n16 = lane & 15, kg = lane >> 4;
    int r = w * 16 + n16;                // block-local row
    long grow0 = rowB + r;
    long cr = (grow0 < N_NODES) ? grow0 : (N_NODES - 1);
    const short8* ap = (const short8*)(Amat + cr * K2 + kg * 8);

    short8 ax[4];                        // x-half A-frags (ks 4..7), global
#pragma unroll
    for (int k = 0; k < 4; ++k) ax[k] = ap[(k + 4) * 4];

    f32x4 acc[8];
#pragma unroll
    for (int ct = 0; ct < 8; ++ct)
        acc[ct] = (f32x4){0.f, 0.f, 0.f, 0.f};

#pragma unroll
    for (int ks = 0; ks < 4; ++ks) {     // agg half from A-lds
        short8 a = *(const short8*)&Alds[r * 256 + ((kg * 16 + ks * 64) ^ ((r & 7) << 4))];
#pragma unroll
        for (int ct = 0; ct < 8; ++ct) {
            short8 b = Wlds[(ct * 8 + ks) * 64 + lane];
            acc[ct] = __builtin_amdgcn_mfma_f32_16x16x32_bf16(a, b, acc[ct], 0, 0, 0);
        }
    }
#pragma unroll
    for (int ks = 4; ks < 8; ++ks) {     // x half from registers
#pragma unroll
        for (int ct = 0; ct < 8; ++ct) {
            short8 b = Wlds[(ct * 8 + ks) * 64 + lane];
            acc[ct] = __builtin_amdgcn_mfma_f32_16x16x32_bf16(ax[ks - 4], b, acc[ct], 0, 0, 0);
        }
    }

    __syncthreads();   // all waves done with Wlds/Alds
    // D layout (m89): col = lane&15, row = 4*(lane>>4) + reg.
#pragma unroll
    for (int ct = 0; ct < 8; ++ct) {
        float bias = brel[ct * 16 + n16];
#pragma unroll
        for (int rr = 0; rr < 4; ++rr) {
            int lrow = w * 16 + kg * 4 + rr;
            int col = ct * 16 + n16;
            So[lrow * 128 + (col ^ ((lrow & 7) << 2))] = acc[ct][rr] + bias;
        }
    }
    __syncthreads();
#pragma unroll
    for (int j = 0; j < 8; ++j) {
        int g = tid + j * 512;
        int lrow = g >> 5;
        int qc = g & 31;
        long grow = rowB + lrow;
        if (grow < N_NODES) {
            float4 v = *(float4*)&So[lrow * 128 + ((qc * 4) ^ ((lrow & 7) << 2))];
            *(float4*)&out[grow * 128 + qc * 4] = v;
        }
    }
}

// ---------------------------------------------------------------------------
// Fallback (ws too small): atomic scatter + fp32 GEMM (round-1 path).
// ---------------------------------------------------------------------------
__global__ void scatter_kernel(const float* __restrict__ x,
                               const int* __restrict__ ei,
                               float* __restrict__ agg) {
    int gid = blockIdx.x * blockDim.x + threadIdx.x;
    int e = gid >> 5;
    if (e >= N_EDGES) return;
    int q = (gid & 31) * 4;
    int s = ei[e];
    int t = ei[N_EDGES + e];
    float4 v = *(const float4*)&x[(size_t)s * D + q];
    float* ap = &agg[(size_t)t * D + q];
    atomicAdd(ap + 0, v.x);
    atomicAdd(ap + 1, v.y);
    atomicAdd(ap + 2, v.z);
    atomicAdd(ap + 3, v.w);
}

__global__ __launch_bounds__(256, 1) void fused_gemm(
        const float* __restrict__ agg, const float* __restrict__ x,
        const float* __restrict__ Wrel, const float* __restrict__ brel,
        const float* __restrict__ Wroot, float* __restrict__ out,
        int nChunks) {
    __shared__ float W2t[256][128];
    __shared__ float rows[16][256];
    int tid = threadIdx.x;
    for (int idx = tid; idx < 256 * 128; idx += 256) {
        int k = idx >> 7, m = idx & 127;
        W2t[k][m] = (k < 128) ? Wrel[m * 128 + k] : Wroot[m * 128 + (k - 128)];
    }
    __syncthreads();
    int mq = tid & 31, rg = tid >> 5, m4 = mq * 4;
    for (int chunk = blockIdx.x; chunk < nChunks; chunk += gridDim.x) {
        size_t row0 = (size_t)chunk * 16;
        __syncthreads();
        for (int j = 0; j < 4; ++j) {
            int i = (tid + j * 256) * 4;
            int r = i >> 8, c = i & 255;
            float4 v;
            if (c < 128) v = *(const float4*)&agg[(row0 + r) * D + c];
            else         v = *(const float4*)&x[(row0 + r) * D + (c - 128)];
            *(float4*)&rows[r][c] = v;
        }
        __syncthreads();
        float4 acc0 = make_float4(0, 0, 0, 0), acc1 = make_float4(0, 0, 0, 0);
#pragma unroll 8
        for (int k = 0; k < 256; ++k) {
            float4 wv = *(const float4*)&W2t[k][m4];
            float A0 = rows[rg][k], A1 = rows[rg + 8][k];
            acc0.x = fmaf(A0, wv.x, acc0.x); acc0.y = fmaf(A0, wv.y, acc0.y);
            acc0.z = fmaf(A0, wv.z, acc0.z); acc0.w = fmaf(A0, wv.w, acc0.w);
            acc1.x = fmaf(A1, wv.x, acc1.x); acc1.y = fmaf(A1, wv.y, acc1.y);
            acc1.z = fmaf(A1, wv.z, acc1.z); acc1.w = fmaf(A1, wv.w, acc1.w);
        }
        float4 b = *(const float4*)&brel[m4];
        *(float4*)&out[(row0 + rg) * D + m4] =
            make_float4(acc0.x + b.x, acc0.y + b.y, acc0.z + b.z, acc0.w + b.w);
        *(float4*)&out[(row0 + rg + 8) * D + m4] =
            make_float4(acc1.x + b.x, acc1.y + b.y, acc1.z + b.z, acc1.w + b.w);
    }
}

extern "C" void kernel_launch(void* const* d_in, const int* in_sizes, int n_in,
                              void* d_out, int out_size, void* d_ws, size_t ws_size,
                              hipStream_t stream) {
    const float* x     = (const float*)d_in[0];
    const int*   ei    = (const int*)d_in[1];
    const float* Wrel  = (const float*)d_in[2];
    const float* brel  = (const float*)d_in[3];
    const float* Wroot = (const float*)d_in[4];
    float* out = (float*)d_out;

    const size_t amatBytes = (size_t)N_NODES * K2 * sizeof(unsigned short); // 51.2 MB
    const size_t off2Bytes = (size_t)N_NODES * 2 * sizeof(int);             // 800 KB
    const size_t srcBytes  = (size_t)NBUCKET * CAPB * sizeof(int);          // 3.6 MB
    const size_t etmpBytes = (size_t)SB_BLOCKS * SB_EDGES * sizeof(unsigned);
    const size_t bboBytes  = (size_t)SB_BLOCKS * (NBUCKET + 1) * sizeof(int);
    const size_t wfBytes   = (size_t)4096 * 8 * sizeof(unsigned short);     // 64 KB
    auto align16 = [](size_t v) { return (v + 15) & ~(size_t)15; };

    size_t o_amat = 0;
    size_t o_off2 = align16(o_amat + amatBytes);
    size_t o_src  = align16(o_off2 + off2Bytes);
    size_t o_etmp = align16(o_src + srcBytes);
    size_t o_bbo  = align16(o_etmp + etmpBytes);
    size_t o_wf   = align16(o_bbo + bboBytes);
    size_t total  = o_wf + wfBytes;

    if (ws_size >= total) {
        char* ws = (char*)d_ws;
        unsigned short* Amat   = (unsigned short*)(ws + o_amat);
        int*      offs2        = (int*)(ws + o_off2);
        int*      srcSortedPad = (int*)(ws + o_src);
        unsigned* edgeTmp      = (unsigned*)(ws + o_etmp);
        int*      blockBucketOff = (int*)(ws + o_bbo);
        unsigned short* Wfrag  = (unsigned short*)(ws + o_wf);

        mega_kernel<<<CONV_BLOCKS + WPREP_BLOCKS + SB_BLOCKS, 256, 0, stream>>>(
            x, Amat, Wrel, Wroot, Wfrag, ei, edgeTmp, blockBucketOff);
        finalize_kernel<<<NBUCKET, 256, 0, stream>>>(edgeTmp, blockBucketOff,
                                                     offs2, srcSortedPad);
        gather_gemm<<<(N_NODES + 127) / 128, 512, 0, stream>>>(
            Amat, Wfrag, offs2, srcSortedPad, brel, out);
    } else {
        // Fallback: atomic scatter + fp32 GEMM.
        float* agg = (ws_size >= (size_t)N_NODES * D * sizeof(float)) ? (float*)d_ws : out;
        hipMemsetAsync(agg, 0, (size_t)N_NODES * D * sizeof(float), stream);
        scatter_kernel<<<(N_EDGES * 32 + 255) / 256, 256, 0, stream>>>(x, ei, agg);
        fused_gemm<<<256, 256, 0, stream>>>(agg, x, Wrel, brel, Wroot, out,
                                            N_NODES / 16);
    }
}

// Round 14
// 89.202 us; speedup vs baseline: 1.3942x; 1.3942x over previous
//
#include <hip/hip_runtime.h>

#define N_NODES 100000
#define N_EDGES 600000
#define D 128
#define K2 256          // stacked K = [agg | x]

#define NBUCKET 196        // ceil(N_NODES / 512); bucket = dst >> 9
#define SB_EPT 8
#define SB_EDGES (256 * SB_EPT)                          // 2048 edges/block
#define SB_BLOCKS ((N_EDGES + SB_EDGES - 1) / SB_EDGES)  // 293
#define CAPB 4608          // padded per-bucket capacity (mean 3072, sigma~55)

#define CONV_BLOCKS 6250   // N_NODES*16 / 256 exactly
#define WPREP_BLOCKS 16    // 4096 slots / 256

typedef __attribute__((ext_vector_type(8))) short short8;
typedef __attribute__((ext_vector_type(4))) float f32x4;

__device__ __forceinline__ unsigned short f2bf(float f) {
    union { float f; unsigned u; } v; v.f = f;
    unsigned u = v.u;
    u += 0x7FFFu + ((u >> 16) & 1u);     // round-to-nearest-even
    return (unsigned short)(u >> 16);
}

__device__ __forceinline__ float bf_lo(unsigned u) {
    union { unsigned u; float f; } v; v.u = u << 16; return v.f;
}
__device__ __forceinline__ float bf_hi(unsigned u) {
    union { unsigned u; float f; } v; v.u = u & 0xFFFF0000u; return v.f;
}

// ---------------------------------------------------------------------------
// mega: fused {convert_x | wprep | local_sort}.  All three block families
// are mutually independent (local_sort needs NO global state: each block
// writes its own edgeTmp region + per-block bucket offset table).
// ---------------------------------------------------------------------------
__global__ __launch_bounds__(256) void mega_kernel(
        const float* __restrict__ x,
        unsigned short* __restrict__ Amat,
        const float* __restrict__ Wrel,
        const float* __restrict__ Wroot,
        unsigned short* __restrict__ Wfrag,
        const int* __restrict__ ei,
        unsigned* __restrict__ edgeTmp,
        int* __restrict__ blockBucketOff) {
    __shared__ int cnt[NBUCKET];
    __shared__ int pos[NBUCKET];
    __shared__ int sh[256];
    int b = blockIdx.x;
    int tid = threadIdx.x;
    if (b < CONV_BLOCKS) {
        // convert_x: x fp32 -> Amat[:,128:256) bf16
        int t = b * 256 + tid;                  // < 1.6M exactly
        int n = t >> 4, c8 = (t & 15) * 8;
        const float4* p = (const float4*)&x[(size_t)n * D + c8];
        float4 v0 = p[0], v1 = p[1];
        uint4 o;
        o.x = (unsigned)f2bf(v0.x) | ((unsigned)f2bf(v0.y) << 16);
        o.y = (unsigned)f2bf(v0.z) | ((unsigned)f2bf(v0.w) << 16);
        o.z = (unsigned)f2bf(v1.x) | ((unsigned)f2bf(v1.y) << 16);
        o.w = (unsigned)f2bf(v1.z) | ((unsigned)f2bf(v1.w) << 16);
        *(uint4*)&Amat[(size_t)n * K2 + 128 + c8] = o;
    } else if (b < CONV_BLOCKS + WPREP_BLOCKS) {
        // wprep: pack [Wrel;Wroot] into MFMA B-fragment order, bf16.
        int slot = (b - CONV_BLOCKS) * 256 + tid;   // < 4096 exactly
        int lane = slot & 63;
        int ks = (slot >> 6) & 7;
        int ct = slot >> 9;
        int m = ct * 16 + (lane & 15);
        int k = ks * 32 + (lane >> 4) * 8;
        const float* src = (k < 128) ? &Wrel[(size_t)m * 128 + k]
                                     : &Wroot[(size_t)m * 128 + (k - 128)];
        uint4 o;
        o.x = (unsigned)f2bf(src[0]) | ((unsigned)f2bf(src[1]) << 16);
        o.y = (unsigned)f2bf(src[2]) | ((unsigned)f2bf(src[3]) << 16);
        o.z = (unsigned)f2bf(src[4]) | ((unsigned)f2bf(src[5]) << 16);
        o.w = (unsigned)f2bf(src[6]) | ((unsigned)f2bf(src[7]) << 16);
        *(uint4*)&Wfrag[(size_t)slot * 8] = o;
    } else {
        // local_sort: bucket-group this block's 2048 edges into its OWN
        // edgeTmp region; write per-block bucket offsets (197 ints).
        int sb = b - CONV_BLOCKS - WPREP_BLOCKS;
        for (int i = tid; i < NBUCKET; i += 256) cnt[i] = 0;
        __syncthreads();
        int e0 = sb * SB_EDGES + tid;
        unsigned pack[SB_EPT];
        int bk[SB_EPT], rk[SB_EPT];
#pragma unroll
        for (int j = 0; j < SB_EPT; ++j) {
            int e = e0 + j * 256;
            if (e < N_EDGES) {
                int s = ei[e];
                int d = ei[N_EDGES + e];
                pack[j] = (unsigned)s | ((unsigned)(d & 511) << 17);
                bk[j] = d >> 9;
                rk[j] = atomicAdd(&cnt[bk[j]], 1);
            } else bk[j] = -1;
        }
        __syncthreads();
        int v = (tid < NBUCKET) ? cnt[tid] : 0;
        sh[tid] = v;
        __syncthreads();
        for (int off = 1; off < 256; off <<= 1) {
            int u = (tid >= off) ? sh[tid - off] : 0;
            __syncthreads();
            sh[tid] += u;
            __syncthreads();
        }
        int excl = sh[tid] - v;             // tid==196 -> total valid count
        if (tid < NBUCKET) pos[tid] = excl;
        if (tid <= NBUCKET) blockBucketOff[sb * (NBUCKET + 1) + tid] = excl;
        __syncthreads();
#pragma unroll
        for (int j = 0; j < SB_EPT; ++j)
            if (bk[j] >= 0)
                edgeTmp[sb * SB_EDGES + pos[bk[j]] + rk[j]] = pack[j];
    }
}

// ---------------------------------------------------------------------------
// finalize: one block per bucket k.  Gathers the 293 per-block runs of
// bucket k into LDS staging (position-parallel binary search), counts/scans
// the 512 local dsts, writes per-node (beg,end) into offs2 and srcs into
// PADDED srcSortedPad[k*CAPB..].  No global scan anywhere.
// ---------------------------------------------------------------------------
__global__ __launch_bounds__(256) void finalize_kernel(
        const unsigned* __restrict__ edgeTmp,
        const int* __restrict__ blockBucketOff,
        int* __restrict__ offs2, int* __restrict__ srcSortedPad) {
    __shared__ unsigned eLDS[CAPB];      // 18 KB staging
    __shared__ int bs[512], bn[512], bp[513];
    __shared__ int cnt[512], cur[512];
    __shared__ int sh[256];
    int k = blockIdx.x, tid = threadIdx.x;

    for (int b = tid; b < 512; b += 256) { bn[b] = 0; bs[b] = 0; }
    cnt[tid] = 0; cnt[tid + 256] = 0;
    __syncthreads();
    for (int b = tid; b < SB_BLOCKS; b += 256) {
        int s = blockBucketOff[b * (NBUCKET + 1) + k];
        int e = blockBucketOff[b * (NBUCKET + 1) + k + 1];
        bs[b] = s;
        bn[b] = e - s;
    }
    __syncthreads();
    int c0 = bn[2 * tid], c1 = bn[2 * tid + 1];
    int ps = c0 + c1;
    sh[tid] = ps;
    __syncthreads();
    for (int off = 1; off < 256; off <<= 1) {
        int u = (tid >= off) ? sh[tid - off] : 0;
        __syncthreads();
        sh[tid] += u;
        __syncthreads();
    }
    int pexcl = sh[tid] - ps;
    bp[2 * tid] = pexcl;
    bp[2 * tid + 1] = pexcl + c0;
    __syncthreads();
    int total = bp[511] + bn[511];
    if (total > CAPB) total = CAPB;      // statistically impossible; safety
    if (tid == 0) bp[512] = total;
    __syncthreads();
    for (int p = tid; p < total; p += 256) {
        int lo = 0, hi = 511;            // largest r with bp[r] <= p
        while (lo < hi) {
            int mid = (lo + hi + 1) >> 1;
            if (bp[mid] <= p) lo = mid; else hi = mid - 1;
        }
        eLDS[p] = edgeTmp[lo * SB_EDGES + bs[lo] + (p - bp[lo])];
    }
    __syncthreads();
    for (int i = tid; i < total; i += 256)
        atomicAdd(&cnt[eLDS[i] >> 17], 1);
    __syncthreads();
    c0 = cnt[2 * tid]; c1 = cnt[2 * tid + 1];
    ps = c0 + c1;
    sh[tid] = ps;
    __syncthreads();
    for (int off = 1; off < 256; off <<= 1) {
        int u = (tid >= off) ? sh[tid - off] : 0;
        __syncthreads();
        sh[tid] += u;
        __syncthreads();
    }
    int base = k * CAPB;
    pexcl = sh[tid] - ps + base;
    cur[2 * tid] = pexcl;
    cur[2 * tid + 1] = pexcl + c0;
    int d = (k << 9) + 2 * tid;
    if (d < N_NODES) {
        offs2[2 * d] = pexcl;
        offs2[2 * d + 1] = pexcl + c0;
    }
    if (d + 1 < N_NODES) {
        offs2[2 * d + 2] = pexcl + c0;
        offs2[2 * d + 3] = pexcl + c0 + c1;
    }
    __syncthreads();
    for (int i = tid; i < total; i += 256) {
        unsigned p = eLDS[i];
        int posn = atomicAdd(&cur[p >> 17], 1);
        srcSortedPad[posn] = (int)(p & 0x1FFFFu);
    }
}

// ---------------------------------------------------------------------------
// seg_sum v5: quarter-wave gather (16 lanes x 16B = one 256B bf16 row per
// instruction); 4 nodes/wave; FOUR edges in flight per quarter (4KB/wave);
// per-node (beg,end) from offs2 (padded layout).  Runs at ~64% occupancy --
// this TLP is what the fused gather_gemm (r13) lost, hence the revert.
// ---------------------------------------------------------------------------
__global__ void seg_sum_kernel(const int* __restrict__ offs2,
                               const int* __restrict__ srcSortedPad,
                               unsigned short* __restrict__ Amat) {
    int wave = (blockIdx.x * blockDim.x + threadIdx.x) >> 6;
    int lane = threadIdx.x & 63;
    int node = wave * 4 + (lane >> 4);
    if (node >= N_NODES) return;
    int c8 = (lane & 15) * 8;          // 8 bf16 cols = 16 B per lane
    int2 be = *(const int2*)&offs2[2 * node];
    int beg = be.x, end = be.y;
    float a0 = 0, a1 = 0, a2 = 0, a3 = 0, a4 = 0, a5 = 0, a6 = 0, a7 = 0;
    int p = beg;
    for (; p + 3 < end; p += 4) {      // 4 independent gathers in flight
        int s0 = srcSortedPad[p],     s1 = srcSortedPad[p + 1];
        int s2 = srcSortedPad[p + 2], s3 = srcSortedPad[p + 3];
        uint4 u0 = *(const uint4*)&Amat[(size_t)s0 * K2 + 128 + c8];
        uint4 u1 = *(const uint4*)&Amat[(size_t)s1 * K2 + 128 + c8];
        uint4 u2 = *(const uint4*)&Amat[(size_t)s2 * K2 + 128 + c8];
        uint4 u3 = *(const uint4*)&Amat[(size_t)s3 * K2 + 128 + c8];
        a0 += (bf_lo(u0.x) + bf_lo(u1.x)) + (bf_lo(u2.x) + bf_lo(u3.x));
        a1 += (bf_hi(u0.x) + bf_hi(u1.x)) + (bf_hi(u2.x) + bf_hi(u3.x));
        a2 += (bf_lo(u0.y) + bf_lo(u1.y)) + (bf_lo(u2.y) + bf_lo(u3.y));
        a3 += (bf_hi(u0.y) + bf_hi(u1.y)) + (bf_hi(u2.y) + bf_hi(u3.y));
        a4 += (bf_lo(u0.z) + bf_lo(u1.z)) + (bf_lo(u2.z) + bf_lo(u3.z));
        a5 += (bf_hi(u0.z) + bf_hi(u1.z)) + (bf_hi(u2.z) + bf_hi(u3.z));
        a6 += (bf_lo(u0.w) + bf_lo(u1.w)) + (bf_lo(u2.w) + bf_lo(u3.w));
        a7 += (bf_hi(u0.w) + bf_hi(u1.w)) + (bf_hi(u2.w) + bf_hi(u3.w));
    }
    for (; p + 1 < end; p += 2) {
        int s0 = srcSortedPad[p], s1 = srcSortedPad[p + 1];
        uint4 u0 = *(const uint4*)&Amat[(size_t)s0 * K2 + 128 + c8];
        uint4 u1 = *(const uint4*)&Amat[(size_t)s1 * K2 + 128 + c8];
        a0 += bf_lo(u0.x) + bf_lo(u1.x);
        a1 += bf_hi(u0.x) + bf_hi(u1.x);
        a2 += bf_lo(u0.y) + bf_lo(u1.y);
        a3 += bf_hi(u0.y) + bf_hi(u1.y);
        a4 += bf_lo(u0.z) + bf_lo(u1.z);
        a5 += bf_hi(u0.z) + bf_hi(u1.z);
        a6 += bf_lo(u0.w) + bf_lo(u1.w);
        a7 += bf_hi(u0.w) + bf_hi(u1.w);
    }
    if (p < end) {
        int s0 = srcSortedPad[p];
        uint4 u0 = *(const uint4*)&Amat[(size_t)s0 * K2 + 128 + c8];
        a0 += bf_lo(u0.x); a1 += bf_hi(u0.x);
        a2 += bf_lo(u0.y); a3 += bf_hi(u0.y);
        a4 += bf_lo(u0.z); a5 += bf_hi(u0.z);
        a6 += bf_lo(u0.w); a7 += bf_hi(u0.w);
    }
    uint4 o;
    o.x = (unsigned)f2bf(a0) | ((unsigned)f2bf(a1) << 16);
    o.y = (unsigned)f2bf(a2) | ((unsigned)f2bf(a3) << 16);
    o.z = (unsigned)f2bf(a4) | ((unsigned)f2bf(a5) << 16);
    o.w = (unsigned)f2bf(a6) | ((unsigned)f2bf(a7) << 16);
    *(uint4*)&Amat[(size_t)node * K2 + c8] = o;
}

// ---------------------------------------------------------------------------
// gemm_mfma v3: 512 threads / 8 waves / 256 rows per block (391 blocks).
// ---------------------------------------------------------------------------
__global__ __launch_bounds__(512, 4) void gemm_mfma(
        const unsigned short* __restrict__ Amat,
        const unsigned short* __restrict__ Wfrag,
        const float* __restrict__ brel,
        float* __restrict__ out) {
    __shared__ __align__(16) char smem[65536];
    short8* Wlds = (short8*)smem;
    float*  So   = (float*)smem;

    int tid = threadIdx.x;
    for (int i = tid; i < 4096; i += 512)
        Wlds[i] = *(const short8*)&Wfrag[(size_t)i * 8];
    __syncthreads();

    int lane = tid & 63;
    int w = tid >> 6;                    // 0..7
    int n16 = lane & 15, kg = lane >> 4;
    long rowB = (long)blockIdx.x * 256;
    long row0 = rowB + w * 32;

    long r0 = row0 + n16;
    long r1 = row0 + 16 + n16;
    long cr0 = (r0 < N_NODES) ? r0 : (N_NODES - 1);
    long cr1 = (r1 < N_NODES) ? r1 : (N_NODES - 1);
    const short8* a0p = (const short8*)(Amat + cr0 * K2 + kg * 8);
    const short8* a1p = (const short8*)(Amat + cr1 * K2 + kg * 8);

    f32x4 acc[2][8];
#pragma unroll
    for (int h = 0; h < 2; ++h)
#pragma unroll
        for (int ct = 0; ct < 8; ++ct)
            acc[h][ct] = (f32x4){0.f, 0.f, 0.f, 0.f};

    short8 a0v[4], a1v[4];
#pragma unroll
    for (int k = 0; k < 4; ++k) { a0v[k] = a0p[k * 4]; a1v[k] = a1p[k * 4]; }
#pragma unroll
    for (int ks = 0; ks < 4; ++ks) {
#pragma unroll
        for (int ct = 0; ct < 8; ++ct) {
            short8 b = Wlds[(ct * 8 + ks) * 64 + lane];
            acc[0][ct] = __builtin_amdgcn_mfma_f32_16x16x32_bf16(a0v[ks], b, acc[0][ct], 0, 0, 0);
            acc[1][ct] = __builtin_amdgcn_mfma_f32_16x16x32_bf16(a1v[ks], b, acc[1][ct], 0, 0, 0);
        }
    }
#pragma unroll
    for (int k = 0; k < 4; ++k) { a0v[k] = a0p[(k + 4) * 4]; a1v[k] = a1p[(k + 4) * 4]; }
#pragma unroll
    for (int ks = 4; ks < 8; ++ks) {
#pragma unroll
        for (int ct = 0; ct < 8; ++ct) {
            short8 b = Wlds[(ct * 8 + ks) * 64 + lane];
            acc[0][ct] = __builtin_amdgcn_mfma_f32_16x16x32_bf16(a0v[ks - 4], b, acc[0][ct], 0, 0, 0);
            acc[1][ct] = __builtin_amdgcn_mfma_f32_16x16x32_bf16(a1v[ks - 4], b, acc[1][ct], 0, 0, 0);
        }
    }

    __syncthreads();   // all waves done reading Wlds
    // D layout (m89): col = lane&15, row = 4*(lane>>4) + reg.
#pragma unroll
    for (int pass = 0; pass < 2; ++pass) {
        if ((w >> 2) == pass) {
            int wl = w & 3;
#pragma unroll
            for (int h = 0; h < 2; ++h)
#pragma unroll
                for (int ct = 0; ct < 8; ++ct) {
                    float bias = brel[ct * 16 + n16];
#pragma unroll
                    for (int r = 0; r < 4; ++r) {
                        int lrow = wl * 32 + h * 16 + kg * 4 + r;
                        int col = ct * 16 + n16;
                        So[lrow * 128 + (col ^ ((lrow & 7) << 2))] = acc[h][ct][r] + bias;
                    }
                }
        }
        __syncthreads();
#pragma unroll
        for (int j = 0; j < 8; ++j) {
            int g = tid + j * 512;
            int lrow = g >> 5;
            int q = g & 31;
            long grow = rowB + pass * 128 + lrow;
            if (grow < N_NODES) {
                float4 v = *(float4*)&So[lrow * 128 + ((q * 4) ^ ((lrow & 7) << 2))];
                *(float4*)&out[grow * 128 + q * 4] = v;
            }
        }
        __syncthreads();
    }
}

// ---------------------------------------------------------------------------
// Fallback (ws too small): atomic scatter + fp32 GEMM (round-1 path).
// ---------------------------------------------------------------------------
__global__ void scatter_kernel(const float* __restrict__ x,
                               const int* __restrict__ ei,
                               float* __restrict__ agg) {
    int gid = blockIdx.x * blockDim.x + threadIdx.x;
    int e = gid >> 5;
    if (e >= N_EDGES) return;
    int q = (gid & 31) * 4;
    int s = ei[e];
    int t = ei[N_EDGES + e];
    float4 v = *(const float4*)&x[(size_t)s * D + q];
    float* ap = &agg[(size_t)t * D + q];
    atomicAdd(ap + 0, v.x);
    atomicAdd(ap + 1, v.y);
    atomicAdd(ap + 2, v.z);
    atomicAdd(ap + 3, v.w);
}

__global__ __launch_bounds__(256, 1) void fused_gemm(
        const float* __restrict__ agg, const float* __restrict__ x,
        const float* __restrict__ Wrel, const float* __restrict__ brel,
        const float* __restrict__ Wroot, float* __restrict__ out,
        int nChunks) {
    __shared__ float W2t[256][128];
    __shared__ float rows[16][256];
    int tid = threadIdx.x;
    for (int idx = tid; idx < 256 * 128; idx += 256) {
        int k = idx >> 7, m = idx & 127;
        W2t[k][m] = (k < 128) ? Wrel[m * 128 + k] : Wroot[m * 128 + (k - 128)];
    }
    __syncthreads();
    int mq = tid & 31, rg = tid >> 5, m4 = mq * 4;
    for (int chunk = blockIdx.x; chunk < nChunks; chunk += gridDim.x) {
        size_t row0 = (size_t)chunk * 16;
        __syncthreads();
        for (int j = 0; j < 4; ++j) {
            int i = (tid + j * 256) * 4;
            int r = i >> 8, c = i & 255;
            float4 v;
            if (c < 128) v = *(const float4*)&agg[(row0 + r) * D + c];
            else         v = *(const float4*)&x[(row0 + r) * D + (c - 128)];
            *(float4*)&rows[r][c] = v;
        }
        __syncthreads();
        float4 acc0 = make_float4(0, 0, 0, 0), acc1 = make_float4(0, 0, 0, 0);
#pragma unroll 8
        for (int k = 0; k < 256; ++k) {
            float4 wv = *(const float4*)&W2t[k][m4];
            float A0 = rows[rg][k], A1 = rows[rg + 8][k];
            acc0.x = fmaf(A0, wv.x, acc0.x); acc0.y = fmaf(A0, wv.y, acc0.y);
            acc0.z = fmaf(A0, wv.z, acc0.z); acc0.w = fmaf(A0, wv.w, acc0.w);
            acc1.x = fmaf(A1, wv.x, acc1.x); acc1.y = fmaf(A1, wv.y, acc1.y);
            acc1.z = fmaf(A1, wv.z, acc1.z); acc1.w = fmaf(A1, wv.w, acc1.w);
        }
        float4 b = *(const float4*)&brel[m4];
        *(float4*)&out[(row0 + rg) * D + m4] =
            make_float4(acc0.x + b.x, acc0.y + b.y, acc0.z + b.z, acc0.w + b.w);
        *(float4*)&out[(row0 + rg + 8) * D + m4] =
            make_float4(acc1.x + b.x, acc1.y + b.y, acc1.z + b.z, acc1.w + b.w);
    }
}

extern "C" void kernel_launch(void* const* d_in, const int* in_sizes, int n_in,
                              void* d_out, int out_size, void* d_ws, size_t ws_size,
                              hipStream_t stream) {
    const float* x     = (const float*)d_in[0];
    const int*   ei    = (const int*)d_in[1];
    const float* Wrel  = (const float*)d_in[2];
    const float* brel  = (const float*)d_in[3];
    const float* Wroot = (const float*)d_in[4];
    float* out = (float*)d_out;

    const size_t amatBytes = (size_t)N_NODES * K2 * sizeof(unsigned short); // 51.2 MB
    const size_t off2Bytes = (size_t)N_NODES * 2 * sizeof(int);             // 800 KB
    const size_t srcBytes  = (size_t)NBUCKET * CAPB * sizeof(int);          // 3.6 MB
    const size_t etmpBytes = (size_t)SB_BLOCKS * SB_EDGES * sizeof(unsigned);
    const size_t bboBytes  = (size_t)SB_BLOCKS * (NBUCKET + 1) * sizeof(int);
    const size_t wfBytes   = (size_t)4096 * 8 * sizeof(unsigned short);     // 64 KB
    auto align16 = [](size_t v) { return (v + 15) & ~(size_t)15; };

    size_t o_amat = 0;
    size_t o_off2 = align16(o_amat + amatBytes);
    size_t o_src  = align16(o_off2 + off2Bytes);
    size_t o_etmp = align16(o_src + srcBytes);
    size_t o_bbo  = align16(o_etmp + etmpBytes);
    size_t o_wf   = align16(o_bbo + bboBytes);
    size_t total  = o_wf + wfBytes;

    if (ws_size >= total) {
        char* ws = (char*)d_ws;
        unsigned short* Amat   = (unsigned short*)(ws + o_amat);
        int*      offs2        = (int*)(ws + o_off2);
        int*      srcSortedPad = (int*)(ws + o_src);
        unsigned* edgeTmp      = (unsigned*)(ws + o_etmp);
        int*      blockBucketOff = (int*)(ws + o_bbo);
        unsigned short* Wfrag  = (unsigned short*)(ws + o_wf);

        mega_kernel<<<CONV_BLOCKS + WPREP_BLOCKS + SB_BLOCKS, 256, 0, stream>>>(
            x, Amat, Wrel, Wroot, Wfrag, ei, edgeTmp, blockBucketOff);
        finalize_kernel<<<NBUCKET, 256, 0, stream>>>(edgeTmp, blockBucketOff,
                                                     offs2, srcSortedPad);
        seg_sum_kernel<<<(N_NODES / 4 * 64 + 255) / 256, 256, 0, stream>>>(
            offs2, srcSortedPad, Amat);
        gemm_mfma<<<(N_NODES + 255) / 256, 512, 0, stream>>>(Amat, Wfrag, brel, out);
    } else {
        // Fallback: atomic scatter + fp32 GEMM.
        float* agg = (ws_size >= (size_t)N_NODES * D * sizeof(float)) ? (float*)d_ws : out;
        hipMemsetAsync(agg, 0, (size_t)N_NODES * D * sizeof(float), stream);
        scatter_kernel<<<(N_EDGES * 32 + 255) / 256, 256, 0, stream>>>(x, ei, agg);
        fused_gemm<<<256, 256, 0, stream>>>(agg, x, Wrel, brel, Wroot, out,
                                            N_NODES / 16);
    }
}